// Round 1
// baseline (607.170 us; speedup 1.0000x reference)
//
#include <hip/hip_runtime.h>
#include <hip/hip_bf16.h>
#include <cstdint>

#define NF_   4
#define NLOC_ 4096
#define NALL_ 4096
#define NNEI_ 128
#define RCUT_ 6.0f
#define RMIN_ 0.5f

// fast tanh via hardware exp + rcp: tanh(x) = 1 - 2/(exp(2x)+1)
// handles saturation correctly: exp(+inf)->inf -> 1 ; exp(-inf)->0 -> -1
__device__ __forceinline__ float fast_tanh(float x) {
    float e = __expf(2.0f * x);
    return 1.0f - 2.0f * __builtin_amdgcn_rcpf(e + 1.0f);
}

__global__ __launch_bounds__(128)
void descrpt_sea_kernel(
    const float* __restrict__ coord,
    const float* __restrict__ davg,
    const float* __restrict__ dstd,
    const float* __restrict__ w1, const float* __restrict__ b1,
    const float* __restrict__ w2, const float* __restrict__ b2,
    const float* __restrict__ w3, const float* __restrict__ b3,
    const int*   __restrict__ nlist,
    float* __restrict__ out)
{
    __shared__ float envs[NNEI_ * 4];   // normalized env, [n][4]
    __shared__ float Gs[NNEI_ * 49];    // one 48-wide half of G, stride 49 (17 mod 32 -> conflict-free)
    __shared__ float Ts[4 * 96];        // T[d][m]

    const int t = threadIdx.x;          // neighbor slot
    const int a = blockIdx.x;           // atom id (f*NLOC + i)
    const int f = a >> 12;
    const int i = a & 4095;

    // ---- phase 1: environment matrix row for this neighbor ----
    const float* cf = coord + (size_t)f * (NALL_ * 3);
    const float cix = cf[i * 3 + 0];    // uniform -> scalar loads
    const float ciy = cf[i * 3 + 1];
    const float ciz = cf[i * 3 + 2];
    const int nb = nlist[(size_t)a * NNEI_ + t];
    float dx = cf[nb * 3 + 0] - cix;
    float dy = cf[nb * 3 + 1] - ciy;
    float dz = cf[nb * 3 + 2] - ciz;
    float r2 = fmaf(dx, dx, fmaf(dy, dy, dz * dz)) + 1e-12f;
    float r  = __builtin_amdgcn_sqrtf(r2);
    float rinv = __builtin_amdgcn_rcpf(r);
    float uu = (r - RMIN_) * (1.0f / (RCUT_ - RMIN_));
    float u2 = uu * uu;
    float mid = (uu * u2) * fmaf(-6.0f, u2, fmaf(15.0f, uu, -10.0f)) + 1.0f;
    float sw  = (r < RMIN_) ? 1.0f : ((r < RCUT_) ? mid : 0.0f);
    float sv  = sw * rinv;
    float e0 = sv;
    float e1 = sv * dx * rinv;
    float e2 = sv * dy * rinv;
    float e3 = sv * dz * rinv;
    const float4 da  = reinterpret_cast<const float4*>(davg)[t];
    const float4 dsd = reinterpret_cast<const float4*>(dstd)[t];
    e0 = (e0 - da.x) * __builtin_amdgcn_rcpf(dsd.x);
    e1 = (e1 - da.y) * __builtin_amdgcn_rcpf(dsd.y);
    e2 = (e2 - da.z) * __builtin_amdgcn_rcpf(dsd.z);
    e3 = (e3 - da.w) * __builtin_amdgcn_rcpf(dsd.w);
    envs[t * 4 + 0] = e0;
    envs[t * 4 + 1] = e1;
    envs[t * 4 + 2] = e2;
    envs[t * 4 + 3] = e3;

    // ---- phase 2: embedding MLP on x = env[...,0] ----
    const float x = e0;
    float h1[24];
#pragma unroll
    for (int j = 0; j < 24; ++j)
        h1[j] = fast_tanh(fmaf(x, w1[j], b1[j]));

    float h2[48];
    {
        float acc[48];
#pragma unroll
        for (int k = 0; k < 48; ++k) acc[k] = b2[k];
#pragma unroll
        for (int j = 0; j < 24; ++j) {
            const float hj = h1[j];
#pragma unroll
            for (int k = 0; k < 48; ++k)
                acc[k] = fmaf(hj, w2[j * 48 + k], acc[k]);
        }
#pragma unroll
        for (int k = 0; k < 48; ++k)
            h2[k] = fast_tanh(acc[k]) + h1[(k < 24) ? k : (k - 24)];
    }

    // ---- phase 3: layer 3 in two 48-channel halves, fused with T contraction ----
#pragma unroll 1
    for (int p = 0; p < 2; ++p) {
        const float* w3p = w3 + p * 48;
        const float* b3p = b3 + p * 48;
        float acc[48];
#pragma unroll
        for (int m = 0; m < 48; ++m) acc[m] = b3p[m];
#pragma unroll
        for (int k = 0; k < 48; ++k) {
            const float hk = h2[k];
#pragma unroll
            for (int m = 0; m < 48; ++m)
                acc[m] = fmaf(hk, w3p[k * 96 + m], acc[m]);
        }
        __syncthreads();   // prev contraction finished reading Gs; envs visible (p==0)
#pragma unroll
        for (int m = 0; m < 48; ++m)
            Gs[t * 49 + m] = fast_tanh(acc[m]) + h2[m];   // (p*48+m) % 48 == m
        __syncthreads();

        // T[d][m] = sum_n envs[n][d] * G[n][m] / NNEI  for this half's m
        if (t < 96) {
            const int mcol = (t < 48) ? t : (t - 48);
            const int db   = (t < 48) ? 0 : 2;
            float t0 = 0.0f, t1 = 0.0f;
#pragma unroll 4
            for (int n = 0; n < NNEI_; ++n) {
                const float gv = Gs[n * 49 + mcol];
                const float ea = envs[n * 4 + db];
                const float eb = envs[n * 4 + db + 1];
                t0 = fmaf(ea, gv, t0);
                t1 = fmaf(eb, gv, t1);
            }
            const int mg = p * 48 + mcol;
            Ts[db * 96 + mg]       = t0 * (1.0f / NNEI_);
            Ts[(db + 1) * 96 + mg] = t1 * (1.0f / NNEI_);
        }
    }
    __syncthreads();

    // ---- phase 4: D[m][k] = sum_d T[d][m]*T[d][k], k < 8 ----
    float* outp = out + (size_t)a * 768;
#pragma unroll
    for (int q = 0; q < 6; ++q) {
        const int idx = t + 128 * q;       // 0..767
        const int m = idx >> 3;
        const int k = idx & 7;
        const float d0 = Ts[0 * 96 + m] * Ts[0 * 96 + k];
        const float d1 = Ts[1 * 96 + m] * Ts[1 * 96 + k];
        const float d2 = Ts[2 * 96 + m] * Ts[2 * 96 + k];
        const float d3 = Ts[3 * 96 + m] * Ts[3 * 96 + k];
        outp[idx] = (d0 + d1) + (d2 + d3);
    }
}

extern "C" void kernel_launch(void* const* d_in, const int* in_sizes, int n_in,
                              void* d_out, int out_size, void* d_ws, size_t ws_size,
                              hipStream_t stream) {
    const float* coord = (const float*)d_in[0];
    const float* davg  = (const float*)d_in[1];
    const float* dstd  = (const float*)d_in[2];
    const float* w1    = (const float*)d_in[3];
    const float* b1    = (const float*)d_in[4];
    const float* w2    = (const float*)d_in[5];
    const float* b2    = (const float*)d_in[6];
    const float* w3    = (const float*)d_in[7];
    const float* b3    = (const float*)d_in[8];
    const int*   nlist = (const int*)d_in[9];
    float* outp = (float*)d_out;

    descrpt_sea_kernel<<<dim3(NF_ * NLOC_), dim3(128), 0, stream>>>(
        coord, davg, dstd, w1, b1, w2, b2, w3, b3, nlist, outp);
}

// Round 2
// 531.367 us; speedup vs baseline: 1.1427x; 1.1427x over previous
//
#include <hip/hip_runtime.h>
#include <hip/hip_bf16.h>
#include <cstdint>

#define NF_   4
#define NLOC_ 4096
#define NALL_ 4096
#define NNEI_ 128
#define RCUT_ 6.0f
#define RMIN_ 0.5f

// fast tanh via hardware exp + rcp: tanh(x) = 1 - 2/(exp(2x)+1)
// saturates correctly: exp(+inf)->inf -> 1 ; exp(-inf)->0 -> -1
__device__ __forceinline__ float fast_tanh(float x) {
    float e = __expf(2.0f * x);
    return 1.0f - 2.0f * __builtin_amdgcn_rcpf(e + 1.0f);
}

__device__ __forceinline__ unsigned pack_bf16(float a, float b) {
    unsigned short ua = __builtin_bit_cast(unsigned short, __float2bfloat16(a));
    unsigned short ub = __builtin_bit_cast(unsigned short, __float2bfloat16(b));
    return (unsigned)ua | ((unsigned)ub << 16);
}
// unpack: lo = bits<<16, hi = bits&0xffff0000 (1 VALU op each)
__device__ __forceinline__ float bf16_lo(unsigned u) {
    return __builtin_bit_cast(float, u << 16);
}
__device__ __forceinline__ float bf16_hi(unsigned u) {
    return __builtin_bit_cast(float, u & 0xffff0000u);
}

// LDS budget: envs 2048 + Gs 12800 + Ts 1536 = 16384 B -> 10 blocks/CU (LDS-wise)
__global__ __launch_bounds__(128, 8)
void descrpt_sea_kernel(
    const float* __restrict__ coord,
    const float* __restrict__ davg,
    const float* __restrict__ dstd,
    const float* __restrict__ w1, const float* __restrict__ b1,
    const float* __restrict__ w2, const float* __restrict__ b2,
    const float* __restrict__ w3, const float* __restrict__ b3,
    const int*   __restrict__ nlist,
    float* __restrict__ out)
{
    __shared__ float    envs[NNEI_ * 4];   // normalized env, [n][4]
    __shared__ unsigned Gs[NNEI_ * 25];    // one 48-ch half of G, bf16x2-packed, stride 25 uints
    __shared__ float    Ts[4 * 96];        // T[d][m]

    const int t = threadIdx.x;             // neighbor slot
    const int a = blockIdx.x;              // atom id (f*NLOC + i)
    const int f = a >> 12;
    const int i = a & 4095;

    // ---- phase 1: environment matrix row for this neighbor ----
    const float* cf = coord + (size_t)f * (NALL_ * 3);
    const float cix = cf[i * 3 + 0];       // uniform -> scalar loads
    const float ciy = cf[i * 3 + 1];
    const float ciz = cf[i * 3 + 2];
    const int nb = nlist[(size_t)a * NNEI_ + t];
    float dx = cf[nb * 3 + 0] - cix;
    float dy = cf[nb * 3 + 1] - ciy;
    float dz = cf[nb * 3 + 2] - ciz;
    float r2 = fmaf(dx, dx, fmaf(dy, dy, dz * dz)) + 1e-12f;
    float r  = __builtin_amdgcn_sqrtf(r2);
    float rinv = __builtin_amdgcn_rcpf(r);
    float uu = (r - RMIN_) * (1.0f / (RCUT_ - RMIN_));
    float u2 = uu * uu;
    float mid = (uu * u2) * fmaf(-6.0f, u2, fmaf(15.0f, uu, -10.0f)) + 1.0f;
    float sw  = (r < RMIN_) ? 1.0f : ((r < RCUT_) ? mid : 0.0f);
    float sv  = sw * rinv;
    float e0 = sv;
    float e1 = sv * dx * rinv;
    float e2 = sv * dy * rinv;
    float e3 = sv * dz * rinv;
    const float4 da  = reinterpret_cast<const float4*>(davg)[t];
    const float4 dsd = reinterpret_cast<const float4*>(dstd)[t];
    e0 = (e0 - da.x) * __builtin_amdgcn_rcpf(dsd.x);
    e1 = (e1 - da.y) * __builtin_amdgcn_rcpf(dsd.y);
    e2 = (e2 - da.z) * __builtin_amdgcn_rcpf(dsd.z);
    e3 = (e3 - da.w) * __builtin_amdgcn_rcpf(dsd.w);
    envs[t * 4 + 0] = e0;
    envs[t * 4 + 1] = e1;
    envs[t * 4 + 2] = e2;
    envs[t * 4 + 3] = e3;

    // ---- phase 2: embedding MLP on x = env[...,0] ----
    const float x = e0;
    float h1[24];
#pragma unroll
    for (int j = 0; j < 24; ++j)
        h1[j] = fast_tanh(fmaf(x, w1[j], b1[j]));

    float h2[48];
    {
        float acc[48];
#pragma unroll
        for (int k = 0; k < 48; ++k) acc[k] = b2[k];
#pragma unroll
        for (int j = 0; j < 24; ++j) {
            const float hj = h1[j];
#pragma unroll
            for (int k = 0; k < 48; ++k)
                acc[k] = fmaf(hj, w2[j * 48 + k], acc[k]);
        }
#pragma unroll
        for (int k = 0; k < 48; ++k)
            h2[k] = fast_tanh(acc[k]) + h1[(k < 24) ? k : (k - 24)];
    }

    // ---- phase 3: layer 3 in two 48-channel halves, fused with T contraction ----
#pragma unroll 1
    for (int p = 0; p < 2; ++p) {
        const float* w3p = w3 + p * 48;
        const float* b3p = b3 + p * 48;
        float acc[48];
#pragma unroll
        for (int m = 0; m < 48; ++m) acc[m] = b3p[m];
#pragma unroll
        for (int k = 0; k < 48; ++k) {
            const float hk = h2[k];
#pragma unroll
            for (int m = 0; m < 48; ++m)
                acc[m] = fmaf(hk, w3p[k * 96 + m], acc[m]);
        }
        __syncthreads();   // p==0: envs visible; p==1: prev contraction done reading Gs
        // write this half of G, bf16x2-packed: Gs[t][j] = {g[2j], g[2j+1]}
#pragma unroll
        for (int j = 0; j < 24; ++j) {
            const float g0 = fast_tanh(acc[2 * j])     + h2[2 * j];
            const float g1 = fast_tanh(acc[2 * j + 1]) + h2[2 * j + 1];
            Gs[t * 25 + j] = pack_bf16(g0, g1);
        }
        __syncthreads();

        // T[d][m] = sum_n envs[n][d] * G[n][m] / NNEI  for this half's m
        // lane map: d = t>>5 (0..3), cp = t&31 (column pair, 24 active)
        {
            const int cp = t & 31;
            const int d  = t >> 5;
            if (cp < 24) {
                float t0 = 0.0f, t1 = 0.0f;
#pragma unroll 4
                for (int n = 0; n < NNEI_; ++n) {
                    const unsigned u = Gs[n * 25 + cp];
                    const float ev = envs[n * 4 + d];
                    t0 = fmaf(ev, bf16_lo(u), t0);
                    t1 = fmaf(ev, bf16_hi(u), t1);
                }
                const int mg = p * 48 + 2 * cp;
                Ts[d * 96 + mg]     = t0 * (1.0f / NNEI_);
                Ts[d * 96 + mg + 1] = t1 * (1.0f / NNEI_);
            }
        }
    }
    __syncthreads();

    // ---- phase 4: D[m][k] = sum_d T[d][m]*T[d][k], k < 8 ----
    float* outp = out + (size_t)a * 768;
#pragma unroll
    for (int q = 0; q < 6; ++q) {
        const int idx = t + 128 * q;       // 0..767
        const int m = idx >> 3;
        const int k = idx & 7;
        const float d0 = Ts[0 * 96 + m] * Ts[0 * 96 + k];
        const float d1 = Ts[1 * 96 + m] * Ts[1 * 96 + k];
        const float d2 = Ts[2 * 96 + m] * Ts[2 * 96 + k];
        const float d3 = Ts[3 * 96 + m] * Ts[3 * 96 + k];
        outp[idx] = (d0 + d1) + (d2 + d3);
    }
}

extern "C" void kernel_launch(void* const* d_in, const int* in_sizes, int n_in,
                              void* d_out, int out_size, void* d_ws, size_t ws_size,
                              hipStream_t stream) {
    const float* coord = (const float*)d_in[0];
    const float* davg  = (const float*)d_in[1];
    const float* dstd  = (const float*)d_in[2];
    const float* w1    = (const float*)d_in[3];
    const float* b1    = (const float*)d_in[4];
    const float* w2    = (const float*)d_in[5];
    const float* b2    = (const float*)d_in[6];
    const float* w3    = (const float*)d_in[7];
    const float* b3    = (const float*)d_in[8];
    const int*   nlist = (const int*)d_in[9];
    float* outp = (float*)d_out;

    descrpt_sea_kernel<<<dim3(NF_ * NLOC_), dim3(128), 0, stream>>>(
        coord, davg, dstd, w1, b1, w2, b2, w3, b3, nlist, outp);
}